// Round 5
// baseline (417.287 us; speedup 1.0000x reference)
//
#include <hip/hip_runtime.h>
#include <hip/hip_fp16.h>
#include <stdint.h>

static constexpr int Bc = 16, Cc = 256, Hc = 56, Wc = 56, Gc = 4;
static constexpr int HWc = Hc * Wc;
static constexpr float EPSc = 1e-5f;
static constexpr int ROWB = 72;          // padded w' positions per abytes row
static constexpr int COL0 = 8;           // [8 zero | 56 data | 8 zero]
static constexpr int ROWBYTES = ROWB * 64;  // 4608 B per (b,g,h) row
static constexpr int ZBYTES = 8192;      // zero row area (max read 4928 B)

typedef int i32x4 __attribute__((ext_vector_type(4)));
typedef int i32x16 __attribute__((ext_vector_type(16)));

// ---------------------------------------------------------------------------
// Workspace:
//   ws + 0        : 8192 B zero area (zero "row"; conv reads <= 4928 B)
//   ws + 8192     : abytes [16][4][56][72][64] i8 = 16,515,072 B
//                   (sign bytes +-1; w' pads are 0 -> zero-padding is exact)
//   ws + 16523264 : wbytes [3][4][9][64 o][64 ci] i8 = 442,368 B
//   ws + 16965632 : scales [768] f32
// Overflow note: A-frag reads may run <=320 B past a row's end; they land in
// the next row's leading zero pad (512 B) or, for the very last row, in
// wbytes (allocated; affects only w>=56 garbage lanes, never stored).
// ---------------------------------------------------------------------------

static constexpr int SBS2 = 132;  // sign-byte LDS row stride (128 ch + pad)

__global__ __launch_bounds__(256) void k_prep(
    const float* __restrict__ w, const float* __restrict__ x,
    const float* __restrict__ bias, uint8_t* __restrict__ wbytes,
    float* __restrict__ scales, uint8_t* __restrict__ abytes,
    uint32_t* __restrict__ zero_area) {
  const int t = threadIdx.x;
  if (blockIdx.x < 192) {
    // ---- weight pack: io = blockIdx*4 + wave; lane = ci ----
    const int io = blockIdx.x * 4 + (t >> 6);
    const int i = io >> 8, o = io & 255;
    const int lane = t & 63;
    const float* wp = w + (size_t)io * 576 + lane * 9;
    float v[9];
    float ssum = 0.f, sabs = 0.f;
#pragma unroll
    for (int k = 0; k < 9; ++k) {
      v[k] = wp[k];
      ssum += v[k];
      sabs += fabsf(v[k]);
    }
#pragma unroll
    for (int off = 32; off > 0; off >>= 1) {
      ssum += __shfl_down(ssum, off);
      sabs += __shfl_down(sabs, off);
    }
    const float mean = __shfl(ssum, 0) * (1.f / 576.f);
    const float scale = __shfl(sabs, 0) * (1.f / 576.f);
    const int g = o >> 6, ol = o & 63;
    uint8_t* dst = wbytes + ((size_t)(i * 4 + g) * 9) * 4096 + ol * 64 + lane;
#pragma unroll
    for (int k = 0; k < 9; ++k)
      dst[k * 4096] = (v[k] > mean) ? (uint8_t)1 : (uint8_t)0xFF;
    if (lane == 0) scales[io] = scale;
  } else if (blockIdx.x == 192) {
    // zero area: 512 x 16 B = 8192 B
    uint4 z;
    z.x = z.y = z.z = z.w = 0u;
    ((uint4*)zero_area)[t] = z;
    ((uint4*)zero_area)[t + 256] = z;
  } else {
    // ---- activation pack: block = (b, h, channel-half). Coalesced float4
    // loads + LDS byte transpose; emit +-1 bytes [w'][ci] (u32 copies).
    __shared__ uint8_t sb[Wc * SBS2];  // [w][c_local], 7392 B
    const int bid = blockIdx.x - 193;
    const int b = bid / 112;
    const int rem = bid - b * 112;
    const int h = rem >> 1, chh = rem & 1;  // chh: channels [chh*128, +128)
    const float* xb = x + ((size_t)(b * Cc + chh * 128)) * HWc + h * Wc;
#pragma unroll
    for (int k = 0; k < 7; ++k) {
      const int idx = k * 256 + t;  // [0, 1792) = 128 c x 14 q
      const int cl = idx / 14, q = idx - cl * 14;
      const float4 v = *(const float4*)(xb + (size_t)cl * HWc + q * 4);
      const float bc = bias[chh * 128 + cl];
      sb[(q * 4 + 0) * SBS2 + cl] = (v.x + bc > 0.f) ? 1 : 0xFF;
      sb[(q * 4 + 1) * SBS2 + cl] = (v.y + bc > 0.f) ? 1 : 0xFF;
      sb[(q * 4 + 2) * SBS2 + cl] = (v.z + bc > 0.f) ? 1 : 0xFF;
      sb[(q * 4 + 3) * SBS2 + cl] = (v.w + bc > 0.f) ? 1 : 0xFF;
    }
    __syncthreads();
    // emit: 2 local groups x 72 w' x 16 dwords = 2304 u32 (9 iters)
    for (int idx = t; idx < 2 * ROWB * 16; idx += 256) {
      const int gl = idx / (ROWB * 16);
      const int r = idx - gl * (ROWB * 16);
      const int wp_ = r >> 4, d4 = r & 15;
      uint32_t word = 0;
      if (wp_ >= COL0 && wp_ < COL0 + Wc)
        word = *(const uint32_t*)(sb + (wp_ - COL0) * SBS2 + gl * 64 + d4 * 4);
      const int g = chh * 2 + gl;
      *(uint32_t*)(abytes + ((size_t)((b * Gc + g) * Hc + h)) * ROWBYTES +
                   wp_ * 64 + d4 * 4) = word;
    }
  }
}

// ---------------------------------------------------------------------------
// One branch (dilation D): 9 taps x 2 K-slices of i8 MFMA, acc over K=576.
// A = activations [M=w(32)][K=ci(32)]: lane row = lane&31 (w), 16 B = K-half
// (lane>>5). One dwordx4 per lane from abytes (ci-contiguous).
// B = weights [K=ci(32)][N=o(32)]: lane col = lane&31 (o), same K-split.
// D/C: col = lane&31 = o, row = (reg&3)+8*(reg>>2)+4*(lane>>5) = w.
// Zero pad bytes contribute 0 -> padding exact, no corrections.
// ---------------------------------------------------------------------------
template <int D>
__device__ __forceinline__ void branch_accum(
    const uint8_t* __restrict__ r0, const uint8_t* __restrict__ r1,
    const uint8_t* __restrict__ r2, const uint8_t* __restrict__ wb,
    int ot2048, int laneoff, float sc, float cbm1, float alp,
    float outf0[16], float outf1[16]) {
  i32x16 ac0 = {0, 0, 0, 0, 0, 0, 0, 0, 0, 0, 0, 0, 0, 0, 0, 0};
  i32x16 ac1 = {0, 0, 0, 0, 0, 0, 0, 0, 0, 0, 0, 0, 0, 0, 0, 0};
#pragma unroll
  for (int tap = 0; tap < 9; ++tap) {
    const uint8_t* r = (tap < 3) ? r0 : ((tap < 6) ? r1 : r2);
    const int wsh = (COL0 + D * ((tap % 3) - 1)) * 64 + laneoff;
#pragma unroll
    for (int ks = 0; ks < 2; ++ks) {
      const i32x4 Bf =
          *(const i32x4*)(wb + tap * 4096 + ot2048 + ks * 32 + laneoff);
      const i32x4 A0 = *(const i32x4*)(r + wsh + ks * 32);
      const i32x4 A1 = *(const i32x4*)(r + wsh + 2048 + ks * 32);
      ac0 = __builtin_amdgcn_mfma_i32_32x32x32_i8(A0, Bf, ac0, 0, 0, 0);
      ac1 = __builtin_amdgcn_mfma_i32_32x32x32_i8(A1, Bf, ac1, 0, 0, 0);
    }
  }
#pragma unroll
  for (int q = 0; q < 16; ++q) {
    const float y0 = fmaf(sc, (float)ac0[q], cbm1);
    outf0[q] += fmaxf(y0, 0.f) + alp * fminf(y0, 0.f);
    const float y1 = fmaf(sc, (float)ac1[q], cbm1);
    outf1[q] += fmaxf(y1, 0.f) + alp * fminf(y1, 0.f);
  }
}

// ---------------------------------------------------------------------------
// K2: fused conv(3 branches, i8 MFMA)+bias+RPReLU+sum+LayerNorm.
// Block = (b,h) full row; wave = group g; lane&31 = o col; regs = w rows.
// ---------------------------------------------------------------------------
static constexpr int TS = 60;  // out_tile stride (halfs)

__global__ __launch_bounds__(256, 4) void k_conv_ln(
    const uint8_t* __restrict__ abytes, const uint8_t* __restrict__ zb,
    const uint8_t* __restrict__ wbytes, const float* __restrict__ scales,
    const float* __restrict__ cb, const float* __restrict__ mv1,
    const float* __restrict__ al, const float* __restrict__ mv2,
    const float* __restrict__ gamma, const float* __restrict__ beta,
    float* __restrict__ out) {
  __shared__ __half out_tile[Cc * TS];
  __shared__ float redu[4][Wc], redq[4][Wc];
  __shared__ float mstat[Wc], rstat[Wc];

  const int bid = blockIdx.x;  // b*56 + h
  const int b = bid / Hc, h = bid % Hc;
  const int t = threadIdx.x;
  const int gu = __builtin_amdgcn_readfirstlane(t >> 6);  // group
  const int lane = t & 63, lane31 = lane & 31;
  const int laneoff = lane31 * 64 + (lane >> 5) * 16;

  const uint8_t* ab_g = abytes + (size_t)((b * Gc + gu) * Hc) * ROWBYTES;
  const uint8_t* r1m = (h - 1 >= 0) ? ab_g + (size_t)(h - 1) * ROWBYTES : zb;
  const uint8_t* rmd = ab_g + (size_t)h * ROWBYTES;
  const uint8_t* r1p = (h + 1 < Hc) ? ab_g + (size_t)(h + 1) * ROWBYTES : zb;
  const uint8_t* r3m = (h - 3 >= 0) ? ab_g + (size_t)(h - 3) * ROWBYTES : zb;
  const uint8_t* r3p = (h + 3 < Hc) ? ab_g + (size_t)(h + 3) * ROWBYTES : zb;
  const uint8_t* r5m = (h - 5 >= 0) ? ab_g + (size_t)(h - 5) * ROWBYTES : zb;
  const uint8_t* r5p = (h + 5 < Hc) ? ab_g + (size_t)(h + 5) * ROWBYTES : zb;

  const uint8_t* wb0 = wbytes + (size_t)(0 * Gc + gu) * 9 * 4096;
  const uint8_t* wb1 = wbytes + (size_t)(1 * Gc + gu) * 9 * 4096;
  const uint8_t* wb2 = wbytes + (size_t)(2 * Gc + gu) * 9 * 4096;

#pragma unroll 1
  for (int ot = 0; ot < 2; ++ot) {  // out-ch 32-tiles within the group
    const int o = gu * 64 + ot * 32 + lane31;
    const float sc0 = scales[o], sc1 = scales[256 + o], sc2 = scales[512 + o];
    const float c0 = cb[o] - mv1[o];
    const float c1 = cb[256 + o] - mv1[256 + o];
    const float c2 = cb[512 + o] - mv1[512 + o];
    const float a0 = al[o], a1 = al[256 + o], a2 = al[512 + o];
    const float m2s = mv2[o] + mv2[256 + o] + mv2[512 + o];
    float outf0[16], outf1[16];
#pragma unroll
    for (int q = 0; q < 16; ++q) {
      outf0[q] = m2s;
      outf1[q] = m2s;
    }
    const int ot2048 = ot * 2048;
    branch_accum<1>(r1m, rmd, r1p, wb0, ot2048, laneoff, sc0, c0, a0, outf0, outf1);
    branch_accum<3>(r3m, rmd, r3p, wb1, ot2048, laneoff, sc1, c1, a1, outf0, outf1);
    branch_accum<5>(r5m, rmd, r5p, wb2, ot2048, laneoff, sc2, c2, a2, outf0, outf1);
    // store to LDS tile: w = (q&3) + 8*(q>>2) + 4*(lane>>5) (+32 for mt1)
    const int wbse = 4 * (lane >> 5);
#pragma unroll
    for (int q = 0; q < 16; ++q) {
      const int wl = (q & 3) + 8 * (q >> 2) + wbse;
      out_tile[o * TS + wl] = __float2half(outf0[q]);
      if (wl + 32 < Wc) out_tile[o * TS + 32 + wl] = __float2half(outf1[q]);
    }
  }
  __syncthreads();

  // ---- LN stats (per output column over 256 channels) ----
  if (t < 4 * Wc) {
    const int ww = t % Wc;
    const int cq = t / Wc;
    float s = 0.f, sq = 0.f;
#pragma unroll 4
    for (int c = cq * 64; c < cq * 64 + 64; ++c) {
      const float v = __half2float(out_tile[c * TS + ww]);
      s += v;
      sq = fmaf(v, v, sq);
    }
    redu[cq][ww] = s;
    redq[cq][ww] = sq;
  }
  __syncthreads();
  if (t < Wc) {
    const float s = redu[0][t] + redu[1][t] + redu[2][t] + redu[3][t];
    const float sq = redq[0][t] + redq[1][t] + redq[2][t] + redq[3][t];
    const float mean = s * (1.f / 256.f);
    const float var = sq * (1.f / 256.f) - mean * mean;
    mstat[t] = mean;
    rstat[t] = rsqrtf(var + EPSc);
  }
  __syncthreads();

  // ---- normalize + coalesced store ----
  float* base = out + ((size_t)b * Cc * Hc + h) * Wc;
  for (int idx = t; idx < Cc * Wc; idx += 256) {
    const int c = idx / Wc;
    const int ww = idx - c * Wc;
    const float v = __half2float(out_tile[c * TS + ww]);
    base[(size_t)c * HWc + ww] = (v - mstat[ww]) * rstat[ww] * gamma[c] + beta[c];
  }
}

// ---------------------------------------------------------------------------
extern "C" void kernel_launch(void* const* d_in, const int* in_sizes, int n_in,
                              void* d_out, int out_size, void* d_ws, size_t ws_size,
                              hipStream_t stream) {
  const float* x     = (const float*)d_in[0];
  const float* bias  = (const float*)d_in[1];
  const float* w     = (const float*)d_in[2];
  const float* cb    = (const float*)d_in[3];
  const float* mv1   = (const float*)d_in[4];
  const float* al    = (const float*)d_in[5];
  const float* mv2   = (const float*)d_in[6];
  const float* gamma = (const float*)d_in[7];
  const float* beta  = (const float*)d_in[8];
  float* out = (float*)d_out;

  uint8_t* ws = (uint8_t*)d_ws;
  uint32_t* zero_area = (uint32_t*)ws;
  const uint8_t* zb = ws;
  uint8_t* abytes = ws + ZBYTES;
  const size_t abytes_sz = (size_t)Bc * Gc * Hc * ROWBYTES;  // 16,515,072
  uint8_t* wbytes = abytes + abytes_sz;
  float* scales = (float*)(wbytes + (size_t)3 * Gc * 9 * 4096);

  hipLaunchKernelGGL(k_prep, dim3(192 + 1 + Bc * Hc * 2), dim3(256), 0, stream,
                     w, x, bias, wbytes, scales, abytes, zero_area);
  hipLaunchKernelGGL(k_conv_ln, dim3(Bc * Hc), dim3(256), 0, stream,
                     abytes, zb, wbytes, scales, cb, mv1, al, mv2, gamma, beta,
                     out);
}

// Round 6
// 332.641 us; speedup vs baseline: 1.2545x; 1.2545x over previous
//
#include <hip/hip_runtime.h>
#include <hip/hip_fp16.h>
#include <stdint.h>

static constexpr int Bc = 16, Cc = 256, Hc = 56, Wc = 56, Gc = 4;
static constexpr int HWc = Hc * Wc;
static constexpr float EPSc = 1e-5f;
static constexpr int ROWB = 72;          // padded w' positions per abytes row
static constexpr int COL0 = 8;           // [8 zero | 56 data | 8 zero]
static constexpr int ROWBYTES = ROWB * 64;  // 4608 B per (b,g,h) row
static constexpr int ZBYTES = 8192;      // zero row area (max read 4928 B)

typedef int i32x4 __attribute__((ext_vector_type(4)));
typedef int i32x16 __attribute__((ext_vector_type(16)));
typedef float f32x16 __attribute__((ext_vector_type(16)));

// ---------------------------------------------------------------------------
// Workspace:
//   ws + 0        : 8192 B zero area (zero "row"; conv reads <= 4928 B)
//   ws + 8192     : abytes [16][4][56][72][64] i8 = 16,515,072 B
//                   (sign bytes +-1; w' pads are 0 -> zero-padding is exact)
//   ws + 16523264 : wbytes [3][4][9][64 o][64 ci] i8 = 442,368 B
//   ws + 16965632 : scales [768] f32
// Overflow note: A-frag reads may run <=320 B past a row's end; they land in
// the next row's leading zero pad (512 B) or, for the very last row, in
// wbytes (allocated; affects only w>=56 garbage lanes, never stored).
// ---------------------------------------------------------------------------

static constexpr int SBS2 = 132;  // sign-byte LDS row stride (128 ch + pad)

__global__ __launch_bounds__(256) void k_prep(
    const float* __restrict__ w, const float* __restrict__ x,
    const float* __restrict__ bias, uint8_t* __restrict__ wbytes,
    float* __restrict__ scales, uint8_t* __restrict__ abytes,
    uint32_t* __restrict__ zero_area) {
  const int t = threadIdx.x;
  if (blockIdx.x < 192) {
    // ---- weight pack: io = blockIdx*4 + wave; lane = ci ----
    const int io = blockIdx.x * 4 + (t >> 6);
    const int i = io >> 8, o = io & 255;
    const int lane = t & 63;
    const float* wp = w + (size_t)io * 576 + lane * 9;
    float v[9];
    float ssum = 0.f, sabs = 0.f;
#pragma unroll
    for (int k = 0; k < 9; ++k) {
      v[k] = wp[k];
      ssum += v[k];
      sabs += fabsf(v[k]);
    }
#pragma unroll
    for (int off = 32; off > 0; off >>= 1) {
      ssum += __shfl_down(ssum, off);
      sabs += __shfl_down(sabs, off);
    }
    const float mean = __shfl(ssum, 0) * (1.f / 576.f);
    const float scale = __shfl(sabs, 0) * (1.f / 576.f);
    const int g = o >> 6, ol = o & 63;
    uint8_t* dst = wbytes + ((size_t)(i * 4 + g) * 9) * 4096 + ol * 64 + lane;
#pragma unroll
    for (int k = 0; k < 9; ++k)
      dst[k * 4096] = (v[k] > mean) ? (uint8_t)1 : (uint8_t)0xFF;
    if (lane == 0) scales[io] = scale;
  } else if (blockIdx.x == 192) {
    // zero area: 512 x 16 B = 8192 B
    uint4 z;
    z.x = z.y = z.z = z.w = 0u;
    ((uint4*)zero_area)[t] = z;
    ((uint4*)zero_area)[t + 256] = z;
  } else {
    // ---- activation pack: block = (b, h, channel-half). Coalesced float4
    // loads + LDS byte transpose; emit +-1 bytes [w'][ci] (u32 copies).
    __shared__ uint8_t sb[Wc * SBS2];  // [w][c_local], 7392 B
    const int bid = blockIdx.x - 193;
    const int b = bid / 112;
    const int rem = bid - b * 112;
    const int h = rem >> 1, chh = rem & 1;  // chh: channels [chh*128, +128)
    const float* xb = x + ((size_t)(b * Cc + chh * 128)) * HWc + h * Wc;
#pragma unroll
    for (int k = 0; k < 7; ++k) {
      const int idx = k * 256 + t;  // [0, 1792) = 128 c x 14 q
      const int cl = idx / 14, q = idx - cl * 14;
      const float4 v = *(const float4*)(xb + (size_t)cl * HWc + q * 4);
      const float bc = bias[chh * 128 + cl];
      sb[(q * 4 + 0) * SBS2 + cl] = (v.x + bc > 0.f) ? 1 : 0xFF;
      sb[(q * 4 + 1) * SBS2 + cl] = (v.y + bc > 0.f) ? 1 : 0xFF;
      sb[(q * 4 + 2) * SBS2 + cl] = (v.z + bc > 0.f) ? 1 : 0xFF;
      sb[(q * 4 + 3) * SBS2 + cl] = (v.w + bc > 0.f) ? 1 : 0xFF;
    }
    __syncthreads();
    // emit: 2 local groups x 72 w' x 16 dwords = 2304 u32 (9 iters)
    for (int idx = t; idx < 2 * ROWB * 16; idx += 256) {
      const int gl = idx / (ROWB * 16);
      const int r = idx - gl * (ROWB * 16);
      const int wp_ = r >> 4, d4 = r & 15;
      uint32_t word = 0;
      if (wp_ >= COL0 && wp_ < COL0 + Wc)
        word = *(const uint32_t*)(sb + (wp_ - COL0) * SBS2 + gl * 64 + d4 * 4);
      const int g = chh * 2 + gl;
      *(uint32_t*)(abytes + ((size_t)((b * Gc + g) * Hc + h)) * ROWBYTES +
                   wp_ * 64 + d4 * 4) = word;
    }
  }
}

// ---------------------------------------------------------------------------
// One (branch, ot, mt) tile: 9 taps x 2 K-slices of i8 MFMA, value-returning
// (no array aliasing -> no scratch). A = [M=w(32)][K=ci]: one dwordx4/lane.
// B = [K=ci][N=o(32)]. D/C: col = lane&31 = o, row = (q&3)+8*(q>>2)+4*(l>>5).
// Zero pad bytes contribute 0 -> padding exact.
// ---------------------------------------------------------------------------
__device__ __forceinline__ i32x16 conv_tile(
    const uint8_t* __restrict__ r0, const uint8_t* __restrict__ r1,
    const uint8_t* __restrict__ r2, const uint8_t* __restrict__ wb, int D,
    int aoff, int boff) {
  i32x16 ac = {0, 0, 0, 0, 0, 0, 0, 0, 0, 0, 0, 0, 0, 0, 0, 0};
#pragma unroll
  for (int tap = 0; tap < 9; ++tap) {
    const uint8_t* r = (tap < 3) ? r0 : ((tap < 6) ? r1 : r2);
    const int wsh = (COL0 + D * ((tap % 3) - 1)) * 64 + aoff;
#pragma unroll
    for (int ks = 0; ks < 2; ++ks) {
      const i32x4 Bf = *(const i32x4*)(wb + tap * 4096 + boff + ks * 32);
      const i32x4 A = *(const i32x4*)(r + wsh + ks * 32);
      ac = __builtin_amdgcn_mfma_i32_32x32x32_i8(A, Bf, ac, 0, 0, 0);
    }
  }
  return ac;
}

// ---------------------------------------------------------------------------
// K2: fused conv(3 branches, i8 MFMA)+bias+RPReLU+sum+LayerNorm.
// Block = (b,h) full row; wave = group g; lane&31 = o col; regs = w rows.
// 4 sequential (ot, mt) passes keep live state to one acc + one outf.
// ---------------------------------------------------------------------------
static constexpr int TS = 60;  // out_tile stride (halfs)

__global__ __launch_bounds__(256, 4) void k_conv_ln(
    const uint8_t* __restrict__ abytes, const uint8_t* __restrict__ zb,
    const uint8_t* __restrict__ wbytes, const float* __restrict__ scales,
    const float* __restrict__ cb, const float* __restrict__ mv1,
    const float* __restrict__ al, const float* __restrict__ mv2,
    const float* __restrict__ gamma, const float* __restrict__ beta,
    float* __restrict__ out) {
  __shared__ __half out_tile[Cc * TS];
  __shared__ float redu[4][Wc], redq[4][Wc];
  __shared__ float mstat[Wc], rstat[Wc];

  const int bid = blockIdx.x;  // b*56 + h
  const int b = bid / Hc, h = bid % Hc;
  const int t = threadIdx.x;
  const int gu = __builtin_amdgcn_readfirstlane(t >> 6);  // group
  const int lane = t & 63, lane31 = lane & 31;
  const int laneoff = lane31 * 64 + (lane >> 5) * 16;

  const uint8_t* ab_g = abytes + (size_t)((b * Gc + gu) * Hc) * ROWBYTES;
  const uint8_t* r1m = (h - 1 >= 0) ? ab_g + (size_t)(h - 1) * ROWBYTES : zb;
  const uint8_t* rmd = ab_g + (size_t)h * ROWBYTES;
  const uint8_t* r1p = (h + 1 < Hc) ? ab_g + (size_t)(h + 1) * ROWBYTES : zb;
  const uint8_t* r3m = (h - 3 >= 0) ? ab_g + (size_t)(h - 3) * ROWBYTES : zb;
  const uint8_t* r3p = (h + 3 < Hc) ? ab_g + (size_t)(h + 3) * ROWBYTES : zb;
  const uint8_t* r5m = (h - 5 >= 0) ? ab_g + (size_t)(h - 5) * ROWBYTES : zb;
  const uint8_t* r5p = (h + 5 < Hc) ? ab_g + (size_t)(h + 5) * ROWBYTES : zb;

  const uint8_t* wb0 = wbytes + (size_t)(0 * Gc + gu) * 9 * 4096;
  const uint8_t* wb1 = wbytes + (size_t)(1 * Gc + gu) * 9 * 4096;
  const uint8_t* wb2 = wbytes + (size_t)(2 * Gc + gu) * 9 * 4096;

#pragma unroll 1
  for (int ot = 0; ot < 2; ++ot) {  // out-ch 32-tile within the group
    const int o = gu * 64 + ot * 32 + lane31;
    const float sc0 = scales[o], sc1 = scales[256 + o], sc2 = scales[512 + o];
    const float c0 = cb[o] - mv1[o];
    const float c1 = cb[256 + o] - mv1[256 + o];
    const float c2 = cb[512 + o] - mv1[512 + o];
    const float a0 = al[o], a1 = al[256 + o], a2 = al[512 + o];
    const float m2s = mv2[o] + mv2[256 + o] + mv2[512 + o];
    const int boff = ot * 2048 + laneoff;
#pragma unroll 1
    for (int mt = 0; mt < 2; ++mt) {  // w 32-tile (mt=1: w 32..63, 56+ cut)
      const int aoff = laneoff + mt * 2048;
      f32x16 outf;
#pragma unroll
      for (int q = 0; q < 16; ++q) outf[q] = m2s;
      {
        const i32x16 ac = conv_tile(r1m, rmd, r1p, wb0, 1, aoff, boff);
#pragma unroll
        for (int q = 0; q < 16; ++q) {
          const float y = fmaf(sc0, (float)ac[q], c0);
          outf[q] += fmaxf(y, 0.f) + a0 * fminf(y, 0.f);
        }
      }
      {
        const i32x16 ac = conv_tile(r3m, rmd, r3p, wb1, 3, aoff, boff);
#pragma unroll
        for (int q = 0; q < 16; ++q) {
          const float y = fmaf(sc1, (float)ac[q], c1);
          outf[q] += fmaxf(y, 0.f) + a1 * fminf(y, 0.f);
        }
      }
      {
        const i32x16 ac = conv_tile(r5m, rmd, r5p, wb2, 5, aoff, boff);
#pragma unroll
        for (int q = 0; q < 16; ++q) {
          const float y = fmaf(sc2, (float)ac[q], c2);
          outf[q] += fmaxf(y, 0.f) + a2 * fminf(y, 0.f);
        }
      }
      // store: w = mt*32 + (q&3) + 8*(q>>2) + 4*(lane>>5)
      const int wbse = mt * 32 + 4 * (lane >> 5);
#pragma unroll
      for (int q = 0; q < 16; ++q) {
        const int wl = (q & 3) + 8 * (q >> 2) + wbse;
        if (mt == 0 || wl < Wc)
          out_tile[o * TS + wl] = __float2half(outf[q]);
      }
    }
  }
  __syncthreads();

  // ---- LN stats (per output column over 256 channels) ----
  if (t < 4 * Wc) {
    const int ww = t % Wc;
    const int cq = t / Wc;
    float s = 0.f, sq = 0.f;
#pragma unroll 4
    for (int c = cq * 64; c < cq * 64 + 64; ++c) {
      const float v = __half2float(out_tile[c * TS + ww]);
      s += v;
      sq = fmaf(v, v, sq);
    }
    redu[cq][ww] = s;
    redq[cq][ww] = sq;
  }
  __syncthreads();
  if (t < Wc) {
    const float s = redu[0][t] + redu[1][t] + redu[2][t] + redu[3][t];
    const float sq = redq[0][t] + redq[1][t] + redq[2][t] + redq[3][t];
    const float mean = s * (1.f / 256.f);
    const float var = sq * (1.f / 256.f) - mean * mean;
    mstat[t] = mean;
    rstat[t] = rsqrtf(var + EPSc);
  }
  __syncthreads();

  // ---- normalize + coalesced store ----
  float* base = out + ((size_t)b * Cc * Hc + h) * Wc;
  for (int idx = t; idx < Cc * Wc; idx += 256) {
    const int c = idx / Wc;
    const int ww = idx - c * Wc;
    const float v = __half2float(out_tile[c * TS + ww]);
    base[(size_t)c * HWc + ww] = (v - mstat[ww]) * rstat[ww] * gamma[c] + beta[c];
  }
}

// ---------------------------------------------------------------------------
extern "C" void kernel_launch(void* const* d_in, const int* in_sizes, int n_in,
                              void* d_out, int out_size, void* d_ws, size_t ws_size,
                              hipStream_t stream) {
  const float* x     = (const float*)d_in[0];
  const float* bias  = (const float*)d_in[1];
  const float* w     = (const float*)d_in[2];
  const float* cb    = (const float*)d_in[3];
  const float* mv1   = (const float*)d_in[4];
  const float* al    = (const float*)d_in[5];
  const float* mv2   = (const float*)d_in[6];
  const float* gamma = (const float*)d_in[7];
  const float* beta  = (const float*)d_in[8];
  float* out = (float*)d_out;

  uint8_t* ws = (uint8_t*)d_ws;
  uint32_t* zero_area = (uint32_t*)ws;
  const uint8_t* zb = ws;
  uint8_t* abytes = ws + ZBYTES;
  const size_t abytes_sz = (size_t)Bc * Gc * Hc * ROWBYTES;  // 16,515,072
  uint8_t* wbytes = abytes + abytes_sz;
  float* scales = (float*)(wbytes + (size_t)3 * Gc * 9 * 4096);

  hipLaunchKernelGGL(k_prep, dim3(192 + 1 + Bc * Hc * 2), dim3(256), 0, stream,
                     w, x, bias, wbytes, scales, abytes, zero_area);
  hipLaunchKernelGGL(k_conv_ln, dim3(Bc * Hc), dim3(256), 0, stream,
                     abytes, zb, wbytes, scales, cb, mv1, al, mv2, gamma, beta,
                     out);
}

// Round 7
// 276.303 us; speedup vs baseline: 1.5102x; 1.2039x over previous
//
#include <hip/hip_runtime.h>
#include <hip/hip_fp16.h>
#include <stdint.h>

static constexpr int Bc = 16, Cc = 256, Hc = 56, Wc = 56, Gc = 4;
static constexpr int HWc = Hc * Wc;
static constexpr float EPSc = 1e-5f;
static constexpr int ROWB = 72;          // padded w' positions per abytes row
static constexpr int COL0 = 8;           // [8 zero | 56 data | 8 zero]
static constexpr int ROWBYTES = ROWB * 64;  // 4608 B per (b,g,h) row
static constexpr int ZBYTES = 8192;      // zero row area (max read 4928 B)

typedef int i32x4 __attribute__((ext_vector_type(4)));
typedef int i32x16 __attribute__((ext_vector_type(16)));
typedef float f32x16 __attribute__((ext_vector_type(16)));

// ---------------------------------------------------------------------------
// Workspace:
//   ws + 0        : 8192 B zero area (zero "row"; conv reads <= 4928 B)
//   ws + 8192     : abytes [16][4][56][72][64] i8 = 16,515,072 B
//                   (sign bytes +-1; w' pads are 0 -> zero-padding is exact)
//   ws + 16523264 : wbytes [3][4][9][64 o][64 ci] i8 = 442,368 B
//   ws + 16965632 : scales [768] f32
// Overflow note: A-frag reads may run <=320 B past a row's end; they land in
// the next row's leading zero pad (512 B) or, for the very last row, in
// wbytes (allocated; affects only w>=56 garbage lanes, never stored).
// ---------------------------------------------------------------------------

static constexpr int SBS2 = 132;  // sign-byte LDS row stride (128 ch + pad)

__global__ __launch_bounds__(256) void k_prep(
    const float* __restrict__ w, const float* __restrict__ x,
    const float* __restrict__ bias, uint8_t* __restrict__ wbytes,
    float* __restrict__ scales, uint8_t* __restrict__ abytes,
    uint32_t* __restrict__ zero_area) {
  const int t = threadIdx.x;
  if (blockIdx.x < 192) {
    // ---- weight pack: io = blockIdx*4 + wave; lane = ci ----
    const int io = blockIdx.x * 4 + (t >> 6);
    const int i = io >> 8, o = io & 255;
    const int lane = t & 63;
    const float* wp = w + (size_t)io * 576 + lane * 9;
    float v[9];
    float ssum = 0.f, sabs = 0.f;
#pragma unroll
    for (int k = 0; k < 9; ++k) {
      v[k] = wp[k];
      ssum += v[k];
      sabs += fabsf(v[k]);
    }
#pragma unroll
    for (int off = 32; off > 0; off >>= 1) {
      ssum += __shfl_down(ssum, off);
      sabs += __shfl_down(sabs, off);
    }
    const float mean = __shfl(ssum, 0) * (1.f / 576.f);
    const float scale = __shfl(sabs, 0) * (1.f / 576.f);
    const int g = o >> 6, ol = o & 63;
    uint8_t* dst = wbytes + ((size_t)(i * 4 + g) * 9) * 4096 + ol * 64 + lane;
#pragma unroll
    for (int k = 0; k < 9; ++k)
      dst[k * 4096] = (v[k] > mean) ? (uint8_t)1 : (uint8_t)0xFF;
    if (lane == 0) scales[io] = scale;
  } else if (blockIdx.x == 192) {
    // zero area: 512 x 16 B = 8192 B
    uint4 z;
    z.x = z.y = z.z = z.w = 0u;
    ((uint4*)zero_area)[t] = z;
    ((uint4*)zero_area)[t + 256] = z;
  } else {
    // ---- activation pack: block = (b, h, channel-half). Coalesced float4
    // loads + LDS byte transpose; emit +-1 bytes [w'][ci] (u32 copies).
    __shared__ uint8_t sb[Wc * SBS2];  // [w][c_local], 7392 B
    const int bid = blockIdx.x - 193;
    const int b = bid / 112;
    const int rem = bid - b * 112;
    const int h = rem >> 1, chh = rem & 1;  // chh: channels [chh*128, +128)
    const float* xb = x + ((size_t)(b * Cc + chh * 128)) * HWc + h * Wc;
#pragma unroll
    for (int k = 0; k < 7; ++k) {
      const int idx = k * 256 + t;  // [0, 1792) = 128 c x 14 q
      const int cl = idx / 14, q = idx - cl * 14;
      const float4 v = *(const float4*)(xb + (size_t)cl * HWc + q * 4);
      const float bc = bias[chh * 128 + cl];
      sb[(q * 4 + 0) * SBS2 + cl] = (v.x + bc > 0.f) ? 1 : 0xFF;
      sb[(q * 4 + 1) * SBS2 + cl] = (v.y + bc > 0.f) ? 1 : 0xFF;
      sb[(q * 4 + 2) * SBS2 + cl] = (v.z + bc > 0.f) ? 1 : 0xFF;
      sb[(q * 4 + 3) * SBS2 + cl] = (v.w + bc > 0.f) ? 1 : 0xFF;
    }
    __syncthreads();
    // emit: 2 local groups x 72 w' x 16 dwords = 2304 u32 (9 iters)
    for (int idx = t; idx < 2 * ROWB * 16; idx += 256) {
      const int gl = idx / (ROWB * 16);
      const int r = idx - gl * (ROWB * 16);
      const int wp_ = r >> 4, d4 = r & 15;
      uint32_t word = 0;
      if (wp_ >= COL0 && wp_ < COL0 + Wc)
        word = *(const uint32_t*)(sb + (wp_ - COL0) * SBS2 + gl * 64 + d4 * 4);
      const int g = chh * 2 + gl;
      *(uint32_t*)(abytes + ((size_t)((b * Gc + g) * Hc + h)) * ROWBYTES +
                   wp_ * 64 + d4 * 4) = word;
    }
  }
}

// ---------------------------------------------------------------------------
// One (branch, ot, mt) tile: 9 taps x 2 K-slices of i8 MFMA, value-returning
// (no array aliasing -> no scratch). A = [M=w(32)][K=ci]: one dwordx4/lane.
// B = [K=ci][N=o(32)]. D/C: col = lane&31 = o, row = (q&3)+8*(q>>2)+4*(l>>5).
// Zero pad bytes contribute 0 -> padding exact.
// ---------------------------------------------------------------------------
template <int D>
__device__ __forceinline__ i32x16 conv_tile(
    const uint8_t* __restrict__ r0, const uint8_t* __restrict__ r1,
    const uint8_t* __restrict__ r2, const uint8_t* __restrict__ wb,
    int aoff, int boff) {
  i32x16 ac = {0, 0, 0, 0, 0, 0, 0, 0, 0, 0, 0, 0, 0, 0, 0, 0};
#pragma unroll
  for (int tap = 0; tap < 9; ++tap) {
    const uint8_t* r = (tap < 3) ? r0 : ((tap < 6) ? r1 : r2);
    const int wsh = (COL0 + D * ((tap % 3) - 1)) * 64 + aoff;
#pragma unroll
    for (int ks = 0; ks < 2; ++ks) {
      const i32x4 Bf = *(const i32x4*)(wb + tap * 4096 + boff + ks * 32);
      const i32x4 A = *(const i32x4*)(r + wsh + ks * 32);
      ac = __builtin_amdgcn_mfma_i32_32x32x32_i8(A, Bf, ac, 0, 0, 0);
    }
  }
  return ac;
}

// ---------------------------------------------------------------------------
// K2: fused conv(3 branches, i8 MFMA)+bias+RPReLU+sum+LayerNorm.
// Block = (b,h) full row; wave = group g; lane&31 = o col; regs = w rows.
// 4 sequential (ot, mt) passes keep live state to one acc + one outf.
// __launch_bounds__(256, 2): cap 256 VGPR — (256,4)'s 128-reg cap forced the
// allocator into a 64-reg + scratch-spill regime (r5/r6: 378 MB scratch).
// ---------------------------------------------------------------------------
static constexpr int TS = 60;  // out_tile stride (halfs)

__global__ __launch_bounds__(256, 2) void k_conv_ln(
    const uint8_t* __restrict__ abytes, const uint8_t* __restrict__ zb,
    const uint8_t* __restrict__ wbytes, const float* __restrict__ scales,
    const float* __restrict__ cb, const float* __restrict__ mv1,
    const float* __restrict__ al, const float* __restrict__ mv2,
    const float* __restrict__ gamma, const float* __restrict__ beta,
    float* __restrict__ out) {
  __shared__ __half out_tile[Cc * TS];
  __shared__ float redu[4][Wc], redq[4][Wc];
  __shared__ float mstat[Wc], rstat[Wc];

  const int bid = blockIdx.x;  // b*56 + h
  const int b = bid / Hc, h = bid % Hc;
  const int t = threadIdx.x;
  const int gu = __builtin_amdgcn_readfirstlane(t >> 6);  // group
  const int lane = t & 63, lane31 = lane & 31;
  const int laneoff = lane31 * 64 + (lane >> 5) * 16;

  const uint8_t* ab_g = abytes + (size_t)((b * Gc + gu) * Hc) * ROWBYTES;
  const uint8_t* r1m = (h - 1 >= 0) ? ab_g + (size_t)(h - 1) * ROWBYTES : zb;
  const uint8_t* rmd = ab_g + (size_t)h * ROWBYTES;
  const uint8_t* r1p = (h + 1 < Hc) ? ab_g + (size_t)(h + 1) * ROWBYTES : zb;
  const uint8_t* r3m = (h - 3 >= 0) ? ab_g + (size_t)(h - 3) * ROWBYTES : zb;
  const uint8_t* r3p = (h + 3 < Hc) ? ab_g + (size_t)(h + 3) * ROWBYTES : zb;
  const uint8_t* r5m = (h - 5 >= 0) ? ab_g + (size_t)(h - 5) * ROWBYTES : zb;
  const uint8_t* r5p = (h + 5 < Hc) ? ab_g + (size_t)(h + 5) * ROWBYTES : zb;

  const uint8_t* wb0 = wbytes + (size_t)(0 * Gc + gu) * 9 * 4096;
  const uint8_t* wb1 = wbytes + (size_t)(1 * Gc + gu) * 9 * 4096;
  const uint8_t* wb2 = wbytes + (size_t)(2 * Gc + gu) * 9 * 4096;

#pragma unroll 1
  for (int ot = 0; ot < 2; ++ot) {  // out-ch 32-tile within the group
    const int o = gu * 64 + ot * 32 + lane31;
    const float sc0 = scales[o], sc1 = scales[256 + o], sc2 = scales[512 + o];
    const float c0 = cb[o] - mv1[o];
    const float c1 = cb[256 + o] - mv1[256 + o];
    const float c2 = cb[512 + o] - mv1[512 + o];
    const float a0 = al[o], a1 = al[256 + o], a2 = al[512 + o];
    const float m2s = mv2[o] + mv2[256 + o] + mv2[512 + o];
    const int boff = ot * 2048 + laneoff;
#pragma unroll 1
    for (int mt = 0; mt < 2; ++mt) {  // w 32-tile (mt=1: w 32..63, 56+ cut)
      const int aoff = laneoff + mt * 2048;
      f32x16 outf;
#pragma unroll
      for (int q = 0; q < 16; ++q) outf[q] = m2s;
      {
        const i32x16 ac = conv_tile<1>(r1m, rmd, r1p, wb0, aoff, boff);
#pragma unroll
        for (int q = 0; q < 16; ++q) {
          const float y = fmaf(sc0, (float)ac[q], c0);
          outf[q] += fmaxf(y, 0.f) + a0 * fminf(y, 0.f);
        }
      }
      {
        const i32x16 ac = conv_tile<3>(r3m, rmd, r3p, wb1, aoff, boff);
#pragma unroll
        for (int q = 0; q < 16; ++q) {
          const float y = fmaf(sc1, (float)ac[q], c1);
          outf[q] += fmaxf(y, 0.f) + a1 * fminf(y, 0.f);
        }
      }
      {
        const i32x16 ac = conv_tile<5>(r5m, rmd, r5p, wb2, aoff, boff);
#pragma unroll
        for (int q = 0; q < 16; ++q) {
          const float y = fmaf(sc2, (float)ac[q], c2);
          outf[q] += fmaxf(y, 0.f) + a2 * fminf(y, 0.f);
        }
      }
      // store: w = mt*32 + (q&3) + 8*(q>>2) + 4*(lane>>5)
      const int wbse = mt * 32 + 4 * (lane >> 5);
#pragma unroll
      for (int q = 0; q < 16; ++q) {
        const int wl = (q & 3) + 8 * (q >> 2) + wbse;
        if (mt == 0 || wl < Wc)
          out_tile[o * TS + wl] = __float2half(outf[q]);
      }
    }
  }
  __syncthreads();

  // ---- LN stats (per output column over 256 channels) ----
  if (t < 4 * Wc) {
    const int ww = t % Wc;
    const int cq = t / Wc;
    float s = 0.f, sq = 0.f;
#pragma unroll 4
    for (int c = cq * 64; c < cq * 64 + 64; ++c) {
      const float v = __half2float(out_tile[c * TS + ww]);
      s += v;
      sq = fmaf(v, v, sq);
    }
    redu[cq][ww] = s;
    redq[cq][ww] = sq;
  }
  __syncthreads();
  if (t < Wc) {
    const float s = redu[0][t] + redu[1][t] + redu[2][t] + redu[3][t];
    const float sq = redq[0][t] + redq[1][t] + redq[2][t] + redq[3][t];
    const float mean = s * (1.f / 256.f);
    const float var = sq * (1.f / 256.f) - mean * mean;
    mstat[t] = mean;
    rstat[t] = rsqrtf(var + EPSc);
  }
  __syncthreads();

  // ---- normalize + coalesced store ----
  float* base = out + ((size_t)b * Cc * Hc + h) * Wc;
  for (int idx = t; idx < Cc * Wc; idx += 256) {
    const int c = idx / Wc;
    const int ww = idx - c * Wc;
    const float v = __half2float(out_tile[c * TS + ww]);
    base[(size_t)c * HWc + ww] = (v - mstat[ww]) * rstat[ww] * gamma[c] + beta[c];
  }
}

// ---------------------------------------------------------------------------
extern "C" void kernel_launch(void* const* d_in, const int* in_sizes, int n_in,
                              void* d_out, int out_size, void* d_ws, size_t ws_size,
                              hipStream_t stream) {
  const float* x     = (const float*)d_in[0];
  const float* bias  = (const float*)d_in[1];
  const float* w     = (const float*)d_in[2];
  const float* cb    = (const float*)d_in[3];
  const float* mv1   = (const float*)d_in[4];
  const float* al    = (const float*)d_in[5];
  const float* mv2   = (const float*)d_in[6];
  const float* gamma = (const float*)d_in[7];
  const float* beta  = (const float*)d_in[8];
  float* out = (float*)d_out;

  uint8_t* ws = (uint8_t*)d_ws;
  uint32_t* zero_area = (uint32_t*)ws;
  const uint8_t* zb = ws;
  uint8_t* abytes = ws + ZBYTES;
  const size_t abytes_sz = (size_t)Bc * Gc * Hc * ROWBYTES;  // 16,515,072
  uint8_t* wbytes = abytes + abytes_sz;
  float* scales = (float*)(wbytes + (size_t)3 * Gc * 9 * 4096);

  hipLaunchKernelGGL(k_prep, dim3(192 + 1 + Bc * Hc * 2), dim3(256), 0, stream,
                     w, x, bias, wbytes, scales, abytes, zero_area);
  hipLaunchKernelGGL(k_conv_ln, dim3(Bc * Hc), dim3(256), 0, stream,
                     abytes, zb, wbytes, scales, cb, mv1, al, mv2, gamma, beta,
                     out);
}

// Round 8
// 221.317 us; speedup vs baseline: 1.8855x; 1.2484x over previous
//
#include <hip/hip_runtime.h>
#include <hip/hip_fp16.h>
#include <stdint.h>

static constexpr int Bc = 16, Cc = 256, Hc = 56, Wc = 56, Gc = 4;
static constexpr int HWc = Hc * Wc;
static constexpr float EPSc = 1e-5f;
static constexpr int ROWB = 72;          // padded w' positions per abytes row
static constexpr int COL0 = 8;           // [8 zero | 56 data | 8 zero]
static constexpr int ROWBYTES = ROWB * 64;  // 4608 B per (b,g,h) row
static constexpr int ZBYTES = 8192;      // zero row area (max read 4928 B)

typedef int i32x4 __attribute__((ext_vector_type(4)));
typedef int i32x16 __attribute__((ext_vector_type(16)));
typedef float f32x16 __attribute__((ext_vector_type(16)));

// ---------------------------------------------------------------------------
// Workspace:
//   ws + 0        : 8192 B zero area (zero "row"; conv reads <= 4928 B)
//   ws + 8192     : abytes [16][4][56][72][64] i8 = 16,515,072 B
//                   (sign bytes +-1; w' pads are 0 -> zero-padding is exact)
//   ws + 16523264 : wbytes [3][4][9][64 o][64 ci] i8 = 442,368 B
//   ws + 16965632 : scales [768] f32
// Overflow note: A-frag reads may run <=320 B past a row's end; they land in
// the next row's leading zero pad (512 B) or, for the very last row, in
// wbytes (allocated; affects only w>=56 garbage lanes, never stored).
// ---------------------------------------------------------------------------

static constexpr int SBS2 = 132;  // sign-byte LDS row stride (128 ch + pad)

__global__ __launch_bounds__(256) void k_prep(
    const float* __restrict__ w, const float* __restrict__ x,
    const float* __restrict__ bias, uint8_t* __restrict__ wbytes,
    float* __restrict__ scales, uint8_t* __restrict__ abytes,
    uint32_t* __restrict__ zero_area) {
  const int t = threadIdx.x;
  if (blockIdx.x < 192) {
    // ---- weight pack: io = blockIdx*4 + wave; lane = ci ----
    const int io = blockIdx.x * 4 + (t >> 6);
    const int i = io >> 8, o = io & 255;
    const int lane = t & 63;
    const float* wp = w + (size_t)io * 576 + lane * 9;
    float v[9];
    float ssum = 0.f, sabs = 0.f;
#pragma unroll
    for (int k = 0; k < 9; ++k) {
      v[k] = wp[k];
      ssum += v[k];
      sabs += fabsf(v[k]);
    }
#pragma unroll
    for (int off = 32; off > 0; off >>= 1) {
      ssum += __shfl_down(ssum, off);
      sabs += __shfl_down(sabs, off);
    }
    const float mean = __shfl(ssum, 0) * (1.f / 576.f);
    const float scale = __shfl(sabs, 0) * (1.f / 576.f);
    const int g = o >> 6, ol = o & 63;
    uint8_t* dst = wbytes + ((size_t)(i * 4 + g) * 9) * 4096 + ol * 64 + lane;
#pragma unroll
    for (int k = 0; k < 9; ++k)
      dst[k * 4096] = (v[k] > mean) ? (uint8_t)1 : (uint8_t)0xFF;
    if (lane == 0) scales[io] = scale;
  } else if (blockIdx.x == 192) {
    // zero area: 512 x 16 B = 8192 B
    uint4 z;
    z.x = z.y = z.z = z.w = 0u;
    ((uint4*)zero_area)[t] = z;
    ((uint4*)zero_area)[t + 256] = z;
  } else {
    // ---- activation pack: block = (b, h, channel-half). Coalesced float4
    // loads + LDS byte transpose; emit +-1 bytes [w'][ci] (u32 copies).
    __shared__ uint8_t sb[Wc * SBS2];  // [w][c_local], 7392 B
    const int bid = blockIdx.x - 193;
    const int b = bid / 112;
    const int rem = bid - b * 112;
    const int h = rem >> 1, chh = rem & 1;  // chh: channels [chh*128, +128)
    const float* xb = x + ((size_t)(b * Cc + chh * 128)) * HWc + h * Wc;
#pragma unroll
    for (int k = 0; k < 7; ++k) {
      const int idx = k * 256 + t;  // [0, 1792) = 128 c x 14 q
      const int cl = idx / 14, q = idx - cl * 14;
      const float4 v = *(const float4*)(xb + (size_t)cl * HWc + q * 4);
      const float bc = bias[chh * 128 + cl];
      sb[(q * 4 + 0) * SBS2 + cl] = (v.x + bc > 0.f) ? 1 : 0xFF;
      sb[(q * 4 + 1) * SBS2 + cl] = (v.y + bc > 0.f) ? 1 : 0xFF;
      sb[(q * 4 + 2) * SBS2 + cl] = (v.z + bc > 0.f) ? 1 : 0xFF;
      sb[(q * 4 + 3) * SBS2 + cl] = (v.w + bc > 0.f) ? 1 : 0xFF;
    }
    __syncthreads();
    // emit: 2 local groups x 72 w' x 16 dwords = 2304 u32 (9 iters)
    for (int idx = t; idx < 2 * ROWB * 16; idx += 256) {
      const int gl = idx / (ROWB * 16);
      const int r = idx - gl * (ROWB * 16);
      const int wp_ = r >> 4, d4 = r & 15;
      uint32_t word = 0;
      if (wp_ >= COL0 && wp_ < COL0 + Wc)
        word = *(const uint32_t*)(sb + (wp_ - COL0) * SBS2 + gl * 64 + d4 * 4);
      const int g = chh * 2 + gl;
      *(uint32_t*)(abytes + ((size_t)((b * Gc + g) * Hc + h)) * ROWBYTES +
                   wp_ * 64 + d4 * 4) = word;
    }
  }
}

// ---------------------------------------------------------------------------
// One (branch, ot, mt) tile: runtime kh loop (unroll 1) bounds the in-flight
// load window to 12 loads (48 VGPRs) per iteration — at full unroll the
// scheduler hoists all 36 independent loads (144 VGPRs) above the serialized
// MFMA chain and spills (r7: ~53 MB scratch each way at VGPR=128).
// A = [M=w(32)][K=ci]: one dwordx4/lane. B = [K=ci][N=o(32)].
// D/C: col = lane&31 = o, row = (q&3)+8*(q>>2)+4*(l>>5). Pad bytes are 0.
// ---------------------------------------------------------------------------
template <int D>
__device__ __forceinline__ i32x16 conv_tile(
    const uint8_t* __restrict__ r0, const uint8_t* __restrict__ r1,
    const uint8_t* __restrict__ r2, const uint8_t* __restrict__ wb,
    int aoff, int boff) {
  i32x16 ac = {0, 0, 0, 0, 0, 0, 0, 0, 0, 0, 0, 0, 0, 0, 0, 0};
#pragma unroll 1
  for (int kh = 0; kh < 3; ++kh) {
    const uint8_t* r = (kh == 0) ? r0 : ((kh == 1) ? r1 : r2);  // scalar csel
    const uint8_t* wt = wb + kh * 3 * 4096 + boff;
#pragma unroll
    for (int ks = 0; ks < 2; ++ks) {
#pragma unroll
      for (int kw = 0; kw < 3; ++kw) {
        const i32x4 Bf = *(const i32x4*)(wt + kw * 4096 + ks * 32);
        const i32x4 A =
            *(const i32x4*)(r + (COL0 + D * (kw - 1)) * 64 + aoff + ks * 32);
        ac = __builtin_amdgcn_mfma_i32_32x32x32_i8(A, Bf, ac, 0, 0, 0);
      }
    }
  }
  return ac;
}

// ---------------------------------------------------------------------------
// K2: fused conv(3 branches, i8 MFMA)+bias+RPReLU+sum+LayerNorm.
// Block = (b,h) full row; wave = group g; lane&31 = o col; regs = w rows.
// XCD-chunked bijective swizzle (896 = 8*112): each XCD owns 112 contiguous
// (b,h) blocks = 2 images = 2.06 MB abytes slice -> L2-resident (re-read
// factor 7 -> ~1) and adjacent 224-B output runs write-combine in L2.
// ---------------------------------------------------------------------------
static constexpr int TS = 60;  // out_tile stride (halfs)

__global__ __launch_bounds__(256, 2) void k_conv_ln(
    const uint8_t* __restrict__ abytes, const uint8_t* __restrict__ zb,
    const uint8_t* __restrict__ wbytes, const float* __restrict__ scales,
    const float* __restrict__ cb, const float* __restrict__ mv1,
    const float* __restrict__ al, const float* __restrict__ mv2,
    const float* __restrict__ gamma, const float* __restrict__ beta,
    float* __restrict__ out) {
  __shared__ __half out_tile[Cc * TS];
  __shared__ float redu[4][Wc], redq[4][Wc];
  __shared__ float mstat[Wc], rstat[Wc];

  const int bid0 = blockIdx.x;                       // hw id (round-robin XCD)
  const int bid = (bid0 & 7) * 112 + (bid0 >> 3);    // b*56 + h, XCD-chunked
  const int b = bid / Hc, h = bid % Hc;
  const int t = threadIdx.x;
  const int gu = __builtin_amdgcn_readfirstlane(t >> 6);  // group
  const int lane = t & 63, lane31 = lane & 31;
  const int laneoff = lane31 * 64 + (lane >> 5) * 16;

  const uint8_t* ab_g = abytes + (size_t)((b * Gc + gu) * Hc) * ROWBYTES;
  const uint8_t* r1m = (h - 1 >= 0) ? ab_g + (size_t)(h - 1) * ROWBYTES : zb;
  const uint8_t* rmd = ab_g + (size_t)h * ROWBYTES;
  const uint8_t* r1p = (h + 1 < Hc) ? ab_g + (size_t)(h + 1) * ROWBYTES : zb;
  const uint8_t* r3m = (h - 3 >= 0) ? ab_g + (size_t)(h - 3) * ROWBYTES : zb;
  const uint8_t* r3p = (h + 3 < Hc) ? ab_g + (size_t)(h + 3) * ROWBYTES : zb;
  const uint8_t* r5m = (h - 5 >= 0) ? ab_g + (size_t)(h - 5) * ROWBYTES : zb;
  const uint8_t* r5p = (h + 5 < Hc) ? ab_g + (size_t)(h + 5) * ROWBYTES : zb;

  const uint8_t* wb0 = wbytes + (size_t)(0 * Gc + gu) * 9 * 4096;
  const uint8_t* wb1 = wbytes + (size_t)(1 * Gc + gu) * 9 * 4096;
  const uint8_t* wb2 = wbytes + (size_t)(2 * Gc + gu) * 9 * 4096;

#pragma unroll 1
  for (int ot = 0; ot < 2; ++ot) {  // out-ch 32-tile within the group
    const int o = gu * 64 + ot * 32 + lane31;
    const float sc0 = scales[o], sc1 = scales[256 + o], sc2 = scales[512 + o];
    const float c0 = cb[o] - mv1[o];
    const float c1 = cb[256 + o] - mv1[256 + o];
    const float c2 = cb[512 + o] - mv1[512 + o];
    const float a0 = al[o], a1 = al[256 + o], a2 = al[512 + o];
    const float m2s = mv2[o] + mv2[256 + o] + mv2[512 + o];
    const int boff = ot * 2048 + laneoff;
#pragma unroll 1
    for (int mt = 0; mt < 2; ++mt) {  // w 32-tile (mt=1: w 32..63, 56+ cut)
      const int aoff = laneoff + mt * 2048;
      f32x16 outf;
#pragma unroll
      for (int q = 0; q < 16; ++q) outf[q] = m2s;
      {
        const i32x16 ac = conv_tile<1>(r1m, rmd, r1p, wb0, aoff, boff);
#pragma unroll
        for (int q = 0; q < 16; ++q) {
          const float y = fmaf(sc0, (float)ac[q], c0);
          outf[q] += fmaxf(y, 0.f) + a0 * fminf(y, 0.f);
        }
      }
      {
        const i32x16 ac = conv_tile<3>(r3m, rmd, r3p, wb1, aoff, boff);
#pragma unroll
        for (int q = 0; q < 16; ++q) {
          const float y = fmaf(sc1, (float)ac[q], c1);
          outf[q] += fmaxf(y, 0.f) + a1 * fminf(y, 0.f);
        }
      }
      {
        const i32x16 ac = conv_tile<5>(r5m, rmd, r5p, wb2, aoff, boff);
#pragma unroll
        for (int q = 0; q < 16; ++q) {
          const float y = fmaf(sc2, (float)ac[q], c2);
          outf[q] += fmaxf(y, 0.f) + a2 * fminf(y, 0.f);
        }
      }
      // store: w = mt*32 + (q&3) + 8*(q>>2) + 4*(lane>>5)
      const int wbse = mt * 32 + 4 * (lane >> 5);
#pragma unroll
      for (int q = 0; q < 16; ++q) {
        const int wl = (q & 3) + 8 * (q >> 2) + wbse;
        if (mt == 0 || wl < Wc)
          out_tile[o * TS + wl] = __float2half(outf[q]);
      }
    }
  }
  __syncthreads();

  // ---- LN stats (per output column over 256 channels) ----
  if (t < 4 * Wc) {
    const int ww = t % Wc;
    const int cq = t / Wc;
    float s = 0.f, sq = 0.f;
#pragma unroll 4
    for (int c = cq * 64; c < cq * 64 + 64; ++c) {
      const float v = __half2float(out_tile[c * TS + ww]);
      s += v;
      sq = fmaf(v, v, sq);
    }
    redu[cq][ww] = s;
    redq[cq][ww] = sq;
  }
  __syncthreads();
  if (t < Wc) {
    const float s = redu[0][t] + redu[1][t] + redu[2][t] + redu[3][t];
    const float sq = redq[0][t] + redq[1][t] + redq[2][t] + redq[3][t];
    const float mean = s * (1.f / 256.f);
    const float var = sq * (1.f / 256.f) - mean * mean;
    mstat[t] = mean;
    rstat[t] = rsqrtf(var + EPSc);
  }
  __syncthreads();

  // ---- normalize + coalesced store ----
  float* base = out + ((size_t)b * Cc * Hc + h) * Wc;
  for (int idx = t; idx < Cc * Wc; idx += 256) {
    const int c = idx / Wc;
    const int ww = idx - c * Wc;
    const float v = __half2float(out_tile[c * TS + ww]);
    base[(size_t)c * HWc + ww] = (v - mstat[ww]) * rstat[ww] * gamma[c] + beta[c];
  }
}

// ---------------------------------------------------------------------------
extern "C" void kernel_launch(void* const* d_in, const int* in_sizes, int n_in,
                              void* d_out, int out_size, void* d_ws, size_t ws_size,
                              hipStream_t stream) {
  const float* x     = (const float*)d_in[0];
  const float* bias  = (const float*)d_in[1];
  const float* w     = (const float*)d_in[2];
  const float* cb    = (const float*)d_in[3];
  const float* mv1   = (const float*)d_in[4];
  const float* al    = (const float*)d_in[5];
  const float* mv2   = (const float*)d_in[6];
  const float* gamma = (const float*)d_in[7];
  const float* beta  = (const float*)d_in[8];
  float* out = (float*)d_out;

  uint8_t* ws = (uint8_t*)d_ws;
  uint32_t* zero_area = (uint32_t*)ws;
  const uint8_t* zb = ws;
  uint8_t* abytes = ws + ZBYTES;
  const size_t abytes_sz = (size_t)Bc * Gc * Hc * ROWBYTES;  // 16,515,072
  uint8_t* wbytes = abytes + abytes_sz;
  float* scales = (float*)(wbytes + (size_t)3 * Gc * 9 * 4096);

  hipLaunchKernelGGL(k_prep, dim3(192 + 1 + Bc * Hc * 2), dim3(256), 0, stream,
                     w, x, bias, wbytes, scales, abytes, zero_area);
  hipLaunchKernelGGL(k_conv_ln, dim3(Bc * Hc), dim3(256), 0, stream,
                     abytes, zb, wbytes, scales, cb, mv1, al, mv2, gamma, beta,
                     out);
}